// Round 1
// baseline (47.016 us; speedup 1.0000x reference)
//
#include <hip/hip_runtime.h>

#define NA 512
#define NB 128
#define OUTSTRIDE (3 * NA + 1)   // 1537 floats per batch row
#define SWZ(j) ((j) + ((j) >> 3))  // pad-every-8 swizzle: stride-8 access -> 2-way banks (free)

// Block = 256 threads = 4 waves. Each block: one batch b, 16 consecutive rows.
// Each wave reduces 4 rows sequentially; lane handles 8 contiguous j (2x float4).
__global__ __launch_bounds__(256) void eij_main(const float* __restrict__ fe,
                                                const float* __restrict__ coords,
                                                float* __restrict__ out) {
    const int b    = blockIdx.x >> 5;   // 32 row-groups per batch
    const int rg   = blockIdx.x & 31;
    const int wave = threadIdx.x >> 6;
    const int lane = threadIdx.x & 63;

    __shared__ float sx[NA + (NA >> 3)];
    __shared__ float sy[NA + (NA >> 3)];
    __shared__ float sz[NA + (NA >> 3)];

    // Stage coords[b] (512 x 3 floats) into swizzled SoA LDS.
    const float* cb = coords + (size_t)b * (NA * 3);
    for (int t = threadIdx.x; t < NA * 3; t += 256) {
        int j = t / 3;
        int c = t - 3 * j;
        float v = cb[t];
        int s = SWZ(j);
        if (c == 0) sx[s] = v;
        else if (c == 1) sy[s] = v;
        else sz[s] = v;
    }
    __syncthreads();

    const int l9 = lane * 9;  // SWZ(8*lane + t) == 9*lane + t for t in [0,8)

    #pragma unroll
    for (int rr = 0; rr < 4; ++rr) {
        const int i  = rg * 16 + wave * 4 + rr;
        const int si = SWZ(i);
        const float cix = sx[si], ciy = sy[si], ciz = sz[si];

        const float* rowp = fe + ((size_t)(b * NA + i)) * NA + lane * 8;
        const float4 v0 = *(const float4*)(rowp);
        const float4 v1 = *(const float4*)(rowp + 4);
        const float fv[8] = {v0.x, v0.y, v0.z, v0.w, v1.x, v1.y, v1.z, v1.w};

        float fx = 0.f, fy = 0.f, fz = 0.f, ep = 0.f;
        #pragma unroll
        for (int t = 0; t < 8; ++t) {
            float d  = (fv[t] - 0.5f) * 200.0f;
            float dx = cix - sx[l9 + t];
            float dy = ciy - sy[l9 + t];
            float dz = ciz - sz[l9 + t];
            float r2 = fmaf(dx, dx, fmaf(dy, dy, dz * dz));
            float rinv = (r2 > 0.f) ? rsqrtf(r2) : 0.f;  // diagonal -> 0
            float s = d * rinv;
            fx = fmaf(s, dx, fx);
            fy = fmaf(s, dy, fy);
            fz = fmaf(s, dz, fz);
            ep += s;
        }

        // Wave-level reduction (64 lanes) of 4 partials.
        #pragma unroll
        for (int off = 32; off >= 1; off >>= 1) {
            fx += __shfl_xor(fx, off);
            fy += __shfl_xor(fy, off);
            fz += __shfl_xor(fz, off);
            ep += __shfl_xor(ep, off);
        }

        if (lane == 0) {
            float* ob = out + (size_t)b * OUTSTRIDE;
            ob[i * 3 + 0] = fx;
            ob[i * 3 + 1] = fy;
            ob[i * 3 + 2] = fz;
            unsafeAtomicAdd(ob + 3 * NA, 0.5f * ep);  // HW global_atomic_add_f32
        }
    }
}

__global__ void eij_zero(float* __restrict__ out) {
    int b = threadIdx.x;
    if (b < NB) out[(size_t)b * OUTSTRIDE + 3 * NA] = 0.f;
}

extern "C" void kernel_launch(void* const* d_in, const int* in_sizes, int n_in,
                              void* d_out, int out_size, void* d_ws, size_t ws_size,
                              hipStream_t stream) {
    const float* fe     = (const float*)d_in[0];
    const float* coords = (const float*)d_in[1];
    float* out          = (float*)d_out;

    hipLaunchKernelGGL(eij_zero, dim3(1), dim3(128), 0, stream, out);
    hipLaunchKernelGGL(eij_main, dim3(NB * 32), dim3(256), 0, stream, fe, coords, out);
}

// Round 2
// 44.386 us; speedup vs baseline: 1.0593x; 1.0593x over previous
//
#include <hip/hip_runtime.h>

#define NA 512
#define NB 128
#define OUTSTRIDE (3 * NA + 1)      // 1537 floats per batch row
// skew: j -> j + 4*(j>>6). Chunk c (64 floats) lives at [c*68, c*68+64), still
// 16B-aligned (68%4==0) and contiguous within a chunk, so float4 LDS reads work.
// Bank of chunk c at inner word t: (4c + t) % 32 -> 8 chunks hit disjoint bank
// quads; lanes in different row-groups read the same address (broadcast).
#define SW(j) ((j) + ((((j) >> 6)) << 2))

__device__ __forceinline__ void accum(float f, float X, float Y, float Z,
                                      float cix, float ciy, float ciz,
                                      float& fx, float& fy, float& fz, float& ep) {
    float d  = (f - 0.5f) * 200.0f;
    float dx = cix - X;
    float dy = ciy - Y;
    float dz = ciz - Z;
    float r2 = fmaf(dx, dx, fmaf(dy, dy, dz * dz));
    float rinv = (r2 > 0.f) ? rsqrtf(r2) : 0.f;   // diagonal -> 0 (diff==0 there)
    float s = d * rinv;
    fx = fmaf(s, dx, fx);
    fy = fmaf(s, dy, fy);
    fz = fmaf(s, dz, fz);
    ep += s;
}

// Block = 256 threads = 4 waves; block handles one batch b, 32 consecutive rows.
// Wave w: rows rg*32 + w*8 .. +8. Lane: i_sub = lane>>3 (row), c = lane&7
// (j-chunk of 64). Each lane: 16 independent float4 FE loads + float4 LDS coords.
__global__ __launch_bounds__(256) void eij_main(const float* __restrict__ fe,
                                                const float* __restrict__ coords,
                                                float* __restrict__ out) {
    const int b    = blockIdx.x >> 4;    // 16 row-groups per batch
    const int rg   = blockIdx.x & 15;
    const int w    = threadIdx.x >> 6;
    const int lane = threadIdx.x & 63;
    const int isub = lane >> 3;
    const int c    = lane & 7;

    __shared__ __align__(16) float sx[544];
    __shared__ __align__(16) float sy[544];
    __shared__ __align__(16) float sz[544];
    __shared__ float sE[4];

    // Stage coords[b] (512 x 3) into skewed SoA LDS.
    const float* cb = coords + (size_t)b * (NA * 3);
    for (int t = threadIdx.x; t < NA * 3; t += 256) {
        int j = t / 3;
        int comp = t - 3 * j;
        float v = cb[t];
        int s = SW(j);
        if (comp == 0) sx[s] = v;
        else if (comp == 1) sy[s] = v;
        else sz[s] = v;
    }
    __syncthreads();

    const int i  = rg * 32 + w * 8 + isub;
    const int si = SW(i);
    const float cix = sx[si], ciy = sy[si], ciz = sz[si];

    const float* rowp = fe + ((size_t)(b * NA + i)) * NA + c * 64;
    const int cbase = c * 68;

    float fx = 0.f, fy = 0.f, fz = 0.f, ep = 0.f;
    #pragma unroll 4
    for (int t4 = 0; t4 < 16; ++t4) {
        const float4 f = *(const float4*)(rowp + t4 * 4);
        const float4 X = *(const float4*)(&sx[cbase + t4 * 4]);
        const float4 Y = *(const float4*)(&sy[cbase + t4 * 4]);
        const float4 Z = *(const float4*)(&sz[cbase + t4 * 4]);
        accum(f.x, X.x, Y.x, Z.x, cix, ciy, ciz, fx, fy, fz, ep);
        accum(f.y, X.y, Y.y, Z.y, cix, ciy, ciz, fx, fy, fz, ep);
        accum(f.z, X.z, Y.z, Z.z, cix, ciy, ciz, fx, fy, fz, ep);
        accum(f.w, X.w, Y.w, Z.w, cix, ciy, ciz, fx, fy, fz, ep);
    }

    // Reduce F across the 8 j-chunks (lanes xor 1,2,4 within each row group).
    #pragma unroll
    for (int off = 1; off <= 4; off <<= 1) {
        fx += __shfl_xor(fx, off);
        fy += __shfl_xor(fy, off);
        fz += __shfl_xor(fz, off);
        ep += __shfl_xor(ep, off);
    }

    if (c == 0) {
        float* ob = out + (size_t)b * OUTSTRIDE;
        ob[i * 3 + 0] = fx;
        ob[i * 3 + 1] = fy;
        ob[i * 3 + 2] = fz;
    }

    // Finish E reduction across row groups, then block-level via LDS.
    #pragma unroll
    for (int off = 8; off <= 32; off <<= 1)
        ep += __shfl_xor(ep, off);
    if (lane == 0) sE[w] = ep;
    __syncthreads();
    if (threadIdx.x == 0) {
        float e = 0.5f * (sE[0] + sE[1] + sE[2] + sE[3]);
        unsafeAtomicAdd(out + (size_t)b * OUTSTRIDE + 3 * NA, e);  // 16 adds/address
    }
}

__global__ void eij_zero(float* __restrict__ out) {
    int b = threadIdx.x;
    if (b < NB) out[(size_t)b * OUTSTRIDE + 3 * NA] = 0.f;
}

extern "C" void kernel_launch(void* const* d_in, const int* in_sizes, int n_in,
                              void* d_out, int out_size, void* d_ws, size_t ws_size,
                              hipStream_t stream) {
    const float* fe     = (const float*)d_in[0];
    const float* coords = (const float*)d_in[1];
    float* out          = (float*)d_out;

    hipLaunchKernelGGL(eij_zero, dim3(1), dim3(128), 0, stream, out);
    hipLaunchKernelGGL(eij_main, dim3(NB * 16), dim3(256), 0, stream, fe, coords, out);
}